// Round 6
// baseline (478.446 us; speedup 1.0000x reference)
//
#include <hip/hip_runtime.h>
#include <math.h>

#define N_NODES 20000
#define N_EDGES 320000
#define E_TOT   (N_EDGES + N_NODES)
#define HID     128
#define NEG_SLOPE 0.2f
#define MT32    625   // 20000/32 exact

typedef __attribute__((ext_vector_type(8))) short short8;
typedef __attribute__((ext_vector_type(8))) unsigned short u16x8;
typedef __attribute__((ext_vector_type(4))) float f32x4;

__device__ __forceinline__ unsigned short f2b(float f) {
  unsigned u = __builtin_bit_cast(unsigned, f);
  return (unsigned short)((u + 0x7fffu + ((u >> 16) & 1u)) >> 16);
}
__device__ __forceinline__ float b2f(unsigned short h) {
  unsigned u = ((unsigned)h) << 16;
  return __builtin_bit_cast(float, u);
}
__device__ __forceinline__ float lrelu(float x) { return x > 0.f ? x : NEG_SLOPE * x; }

// ---------------- CSR build ----------------
__global__ void k_init_deg(int* __restrict__ deg) {
  int i = blockIdx.x * blockDim.x + threadIdx.x;
  if (i < N_NODES) deg[i] = 1;  // self loop
}

__global__ void k_hist(const int* __restrict__ ei, int* __restrict__ deg) {
  int e = blockIdx.x * blockDim.x + threadIdx.x;
  if (e < N_EDGES) atomicAdd(&deg[ei[N_EDGES + e]], 1);
}

__global__ __launch_bounds__(1024) void k_scan(int* __restrict__ deg,
                                               int* __restrict__ row_ptr) {
  __shared__ int sums[1024];
  int t = threadIdx.x;
  const int CH = 20;
  int begin = t * CH;
  int end = begin + CH; if (end > N_NODES) end = N_NODES;
  int loc = 0;
  for (int i = begin; i < end; ++i) loc += deg[i];
  sums[t] = loc;
  __syncthreads();
  for (int off = 1; off < 1024; off <<= 1) {
    int v = (t >= off) ? sums[t - off] : 0;
    __syncthreads();
    sums[t] += v;
    __syncthreads();
  }
  int run = (t > 0) ? sums[t - 1] : 0;
  for (int i = begin; i < end; ++i) {
    int d = deg[i];
    row_ptr[i] = run;
    run += d;
    deg[i] = 0;      // becomes the scatter cursor
  }
  if (t == 1023) row_ptr[N_NODES] = sums[1023];
}

__global__ void k_scatter(const int* __restrict__ ei, const int* __restrict__ row_ptr,
                          int* __restrict__ cursor, int* __restrict__ edge_src) {
  int t = blockIdx.x * blockDim.x + threadIdx.x;
  if (t < N_EDGES) {
    int s = ei[t], d = ei[N_EDGES + t];
    int pos = row_ptr[d] + atomicAdd(&cursor[d], 1);
    edge_src[pos] = s;
  } else if (t < E_TOT) {
    int i = t - N_EDGES;
    int pos = row_ptr[i] + atomicAdd(&cursor[i], 1);
    edge_src[pos] = i;
  }
}

// ---------------- merged weight prep ----------------
struct WtJobs {
  const float* src[8];
  unsigned short* dst[8];
  int K[8], N[8], blk_end[8];
};

__global__ void k_wt_all(WtJobs jb) {
  int b = blockIdx.x;
  int seg = 0;
  while (b >= jb.blk_end[seg]) ++seg;
  int base = seg ? jb.blk_end[seg - 1] : 0;
  int idx = (b - base) * 256 + threadIdx.x;
  int K = jb.K[seg], N = jb.N[seg];
  if (idx < N * K) {
    int n = idx / K, k = idx - n * K;
    jb.dst[seg][idx] = f2b(jb.src[seg][(size_t)k * N + n]);
  }
}

// ---------------- GEMM core: 32x128 tile, 4 waves (1x4), BK=64, reg-prefetch ----------------
// MODE 0: f32 out + bias + relu (LDS-coalesced stores).
// MODE 1: bf16 out (LDS-coalesced) + fused attn logits.
template<int MODE>
__device__ __forceinline__ void gemm_core(
    const float* __restrict__ A, int lda, int c0,
    const unsigned short* __restrict__ Bt,
    const float* __restrict__ bias,
    float* __restrict__ Cf, unsigned short* __restrict__ Cb, int ldc,
    int K, int m0, int n0,
    const float* __restrict__ asrc, const float* __restrict__ adst,
    float* __restrict__ als, float* __restrict__ ald, int head) {
  __shared__ unsigned short sAB[32 * 64 + 128 * 64];   // As | Bs ; reused as C-tile
  __shared__ float attS[32 * 4], attD[32 * 4];
  unsigned short* As = sAB;
  unsigned short* Bs = sAB + 32 * 64;

  int t = threadIdx.x;
  int w = t >> 6, l = t & 63;
  int lr = l & 15, lhi = l >> 4;
  int wn = w * 32;

  int arow = t >> 3, aq = t & 7;        // A: 32 rows x 8 threads of 8 f32
  int brow = t >> 1, bhalf = t & 1;     // B: 128 rows x 2 threads of 32 bf16
  const float* aptr = A + (size_t)(m0 + arow) * lda + c0 + aq * 8;
  const unsigned short* bptr = Bt + (size_t)(n0 + brow) * K + bhalf * 32;

  f32x4 acc[2][2];
  #pragma unroll
  for (int i = 0; i < 2; ++i)
    #pragma unroll
    for (int j = 0; j < 2; ++j) acc[i][j] = (f32x4){0.f, 0.f, 0.f, 0.f};

  float4 ar0 = ((const float4*)aptr)[0];
  float4 ar1 = ((const float4*)aptr)[1];
  uint4 br[4];
  #pragma unroll
  for (int p = 0; p < 4; ++p) br[p] = ((const uint4*)bptr)[p];

  for (int k0 = 0; k0 < K; k0 += 64) {
    uint4 aw;
    aw.x = (unsigned)f2b(ar0.x) | ((unsigned)f2b(ar0.y) << 16);
    aw.y = (unsigned)f2b(ar0.z) | ((unsigned)f2b(ar0.w) << 16);
    aw.z = (unsigned)f2b(ar1.x) | ((unsigned)f2b(ar1.y) << 16);
    aw.w = (unsigned)f2b(ar1.z) | ((unsigned)f2b(ar1.w) << 16);
    *(uint4*)&As[arow * 64 + ((aq ^ (arow & 7)) << 3)] = aw;
    #pragma unroll
    for (int p = 0; p < 4; ++p) {
      int cb = bhalf * 4 + p;
      *(uint4*)&Bs[brow * 64 + ((cb ^ (brow & 7)) << 3)] = br[p];
    }
    __syncthreads();
    if (k0 + 64 < K) {
      ar0 = ((const float4*)(aptr + k0 + 64))[0];
      ar1 = ((const float4*)(aptr + k0 + 64))[1];
      #pragma unroll
      for (int p = 0; p < 4; ++p) br[p] = ((const uint4*)(bptr + k0 + 64))[p];
    }
    #pragma unroll
    for (int kk = 0; kk < 2; ++kk) {
      short8 af[2], bfr[2];
      int cbf = lhi + kk * 4;
      #pragma unroll
      for (int i = 0; i < 2; ++i) {
        int row = i * 16 + lr;
        af[i] = *(const short8*)&As[row * 64 + ((cbf ^ (row & 7)) << 3)];
      }
      #pragma unroll
      for (int j = 0; j < 2; ++j) {
        int nn = wn + j * 16 + lr;
        bfr[j] = *(const short8*)&Bs[nn * 64 + ((cbf ^ (nn & 7)) << 3)];
      }
      #pragma unroll
      for (int i = 0; i < 2; ++i)
        #pragma unroll
        for (int j = 0; j < 2; ++j)
          acc[i][j] = __builtin_amdgcn_mfma_f32_16x16x32_bf16(af[i], bfr[j], acc[i][j], 0, 0, 0);
    }
    __syncthreads();
  }

  if (MODE == 0) {
    float* Ctf = (float*)sAB;   // [32][128] f32 = 16 KB
    #pragma unroll
    for (int i = 0; i < 2; ++i)
      #pragma unroll
      for (int j = 0; j < 2; ++j) {
        int col = wn + j * 16 + lr;
        float bsv = bias[col];
        #pragma unroll
        for (int rr = 0; rr < 4; ++rr) {
          int row = i * 16 + lhi * 4 + rr;
          float v = acc[i][j][rr] + bsv;
          Ctf[row * 128 + col] = fmaxf(v, 0.f);
        }
      }
    __syncthreads();
    int crow = t >> 3, cq = t & 7;
    float4* gdst = (float4*)(Cf + (size_t)(m0 + crow) * ldc + cq * 16);
    const float4* ls = (const float4*)&Ctf[crow * 128 + cq * 16];
    #pragma unroll
    for (int p = 0; p < 4; ++p) gdst[p] = ls[p];
  } else {
    // fused attention logits on bf16-rounded values (match stored xh)
    float asv[2], adv[2];
    #pragma unroll
    for (int j = 0; j < 2; ++j) {
      int col = wn + j * 16 + lr;
      asv[j] = asrc[col];
      adv[j] = adst[col];
    }
    #pragma unroll
    for (int i = 0; i < 2; ++i) {
      #pragma unroll
      for (int rr = 0; rr < 4; ++rr) {
        float ss = 0.f, sd = 0.f;
        #pragma unroll
        for (int j = 0; j < 2; ++j) {
          float v = b2f(f2b(acc[i][j][rr]));
          ss += v * asv[j];
          sd += v * adv[j];
        }
        ss += __shfl_xor(ss, 1); sd += __shfl_xor(sd, 1);
        ss += __shfl_xor(ss, 2); sd += __shfl_xor(sd, 2);
        ss += __shfl_xor(ss, 4); sd += __shfl_xor(sd, 4);
        ss += __shfl_xor(ss, 8); sd += __shfl_xor(sd, 8);
        if (lr == 0) {
          int row = i * 16 + lhi * 4 + rr;
          attS[row * 4 + w] = ss;
          attD[row * 4 + w] = sd;
        }
      }
    }
    unsigned short* Ct = sAB;   // [32][128] bf16 = 8 KB
    #pragma unroll
    for (int i = 0; i < 2; ++i)
      #pragma unroll
      for (int j = 0; j < 2; ++j) {
        int col = wn + j * 16 + lr;
        #pragma unroll
        for (int rr = 0; rr < 4; ++rr) {
          int row = i * 16 + lhi * 4 + rr;
          Ct[row * 128 + col] = f2b(acc[i][j][rr]);
        }
      }
    __syncthreads();
    if (t < 32) {
      int gr = m0 + t;
      als[gr * 4 + head] = attS[t * 4] + attS[t * 4 + 1] + attS[t * 4 + 2] + attS[t * 4 + 3];
      ald[gr * 4 + head] = attD[t * 4] + attD[t * 4 + 1] + attD[t * 4 + 2] + attD[t * 4 + 3];
    }
    int crow = t >> 3, cq = t & 7;
    uint4* gdst = (uint4*)(Cb + (size_t)(m0 + crow) * ldc + n0 + cq * 16);
    const uint4* ls = (const uint4*)&Ct[crow * 128 + cq * 16];
    gdst[0] = ls[0];
    gdst[1] = ls[1];
  }
}

// projections: y=0 vis (K=768), y=1 txt (K=384)
__global__ __launch_bounds__(256) void k_proj(
    const float* __restrict__ x,
    const unsigned short* __restrict__ btv, const unsigned short* __restrict__ btt,
    const float* __restrict__ vb, const float* __restrict__ tb,
    float* __restrict__ hv, float* __restrict__ ht) {
  int m0 = blockIdx.x * 32;
  int c0, K;
  const unsigned short* Bt;
  const float* bias;
  float* Cf;
  if (blockIdx.y == 0) { c0 = 0;   K = 768; Bt = btv; bias = vb; Cf = hv; }
  else                 { c0 = 768; K = 384; Bt = btt; bias = tb; Cf = ht; }
  gemm_core<0>(x, 1152, c0, Bt, bias, Cf, nullptr, 128, K, m0, 0,
               nullptr, nullptr, nullptr, nullptr, 0);
}

// merged layer GEMM + fused attention; y = head + 4*mod
struct LayerArgs {
  const float* h[2];
  const unsigned short* bt[2];
  const float* as_[2];
  const float* ad_[2];
  unsigned short* xb[2];
  float* als[2];
  float* ald[2];
};
__global__ __launch_bounds__(256) void k_layer(LayerArgs a) {
  int m0 = blockIdx.x * 32;
  int head = blockIdx.y & 3, mod = blockIdx.y >> 2;
  gemm_core<1>(a.h[mod], 128, 0, a.bt[mod], nullptr, nullptr, a.xb[mod], 512,
               128, m0, head * 128, a.as_[mod] + head * 128, a.ad_[mod] + head * 128,
               a.als[mod], a.ald[mod], head);
}

// merged head GEMMs: y=0 vision, y=1 text
__global__ __launch_bounds__(256) void k_head(
    const float* __restrict__ hv, const float* __restrict__ ht,
    const unsigned short* __restrict__ btvh, const unsigned short* __restrict__ btth,
    const float* __restrict__ vhb, const float* __restrict__ thb,
    float* __restrict__ out) {
  int m0 = blockIdx.x * 32;
  const float* A;
  const unsigned short* Bt;
  const float* bias;
  float* Cf;
  if (blockIdx.y == 0) { A = hv; Bt = btvh; bias = vhb; Cf = out + 2560000; }
  else                 { A = ht; Bt = btth; bias = thb; Cf = out + 5120000; }
  gemm_core<0>(A, 128, 0, Bt, bias, Cf, nullptr, 128, 128, m0, 0,
               nullptr, nullptr, nullptr, nullptr, 0);
}

// ---------------- fused GAT aggregation, both modalities in one grid ----------------
struct AggArgs {
  const unsigned short* xh[2];
  const float* als[2];
  const float* ald[2];
  const float* bias[2];
  float* h[2];
};
__global__ __launch_bounds__(128) void k_agg(AggArgs ag,
                                             const int* __restrict__ row_ptr,
                                             const int* __restrict__ edge_src) {
  int b = blockIdx.x;
  int mod = b >= N_NODES;
  int node = b - mod * N_NODES;
  const unsigned short* __restrict__ xh = ag.xh[mod];
  const float* __restrict__ als = ag.als[mod];
  const float* __restrict__ ald = ag.ald[mod];
  const float* __restrict__ bias = ag.bias[mod];
  float* __restrict__ h = ag.h[mod];

  int tid = threadIdx.x;  // 0..127
  __shared__ float sp[128][4];
  __shared__ int   ssrc[128];
  __shared__ float sredm[8], sreds[8];
  __shared__ float sout[1024];    // [2 waves][4 heads][128 ch]
  __shared__ float red[4 * 128];  // fallback only
  int begin = row_ptr[node], end = row_ptr[node + 1];
  int deg = end - begin;
  float4 ad4 = *(const float4*)(ald + (size_t)node * 4);
  int wv = tid >> 6;

  if (deg <= 128) {
    float e0 = -1e30f, e1 = -1e30f, e2 = -1e30f, e3 = -1e30f;
    if (tid < deg) {
      int s = edge_src[begin + tid];
      ssrc[tid] = s;
      float4 a4 = *(const float4*)(als + (size_t)s * 4);
      e0 = lrelu(a4.x + ad4.x); e1 = lrelu(a4.y + ad4.y);
      e2 = lrelu(a4.z + ad4.z); e3 = lrelu(a4.w + ad4.w);
    }
    float m0 = e0, m1 = e1, m2 = e2, m3 = e3;
    for (int off = 32; off > 0; off >>= 1) {
      m0 = fmaxf(m0, __shfl_xor(m0, off));
      m1 = fmaxf(m1, __shfl_xor(m1, off));
      m2 = fmaxf(m2, __shfl_xor(m2, off));
      m3 = fmaxf(m3, __shfl_xor(m3, off));
    }
    if ((tid & 63) == 0) {
      sredm[wv * 4 + 0] = m0; sredm[wv * 4 + 1] = m1;
      sredm[wv * 4 + 2] = m2; sredm[wv * 4 + 3] = m3;
    }
    __syncthreads();
    m0 = fmaxf(sredm[0], sredm[4]); m1 = fmaxf(sredm[1], sredm[5]);
    m2 = fmaxf(sredm[2], sredm[6]); m3 = fmaxf(sredm[3], sredm[7]);
    float p0 = 0.f, p1 = 0.f, p2 = 0.f, p3 = 0.f;
    if (tid < deg) {
      p0 = __expf(e0 - m0); p1 = __expf(e1 - m1);
      p2 = __expf(e2 - m2); p3 = __expf(e3 - m3);
    }
    *(float4*)&sp[tid][0] = make_float4(p0, p1, p2, p3);
    float s0 = p0, s1 = p1, s2 = p2, s3 = p3;
    for (int off = 32; off > 0; off >>= 1) {
      s0 += __shfl_xor(s0, off); s1 += __shfl_xor(s1, off);
      s2 += __shfl_xor(s2, off); s3 += __shfl_xor(s3, off);
    }
    if ((tid & 63) == 0) {
      sreds[wv * 4 + 0] = s0; sreds[wv * 4 + 1] = s1;
      sreds[wv * 4 + 2] = s2; sreds[wv * 4 + 3] = s3;
    }
    __syncthreads();

    // phase C: wave wv handles edges wv, wv+2, ... ; lane owns (head, 8 channels)
    int lane = tid & 63;
    int hd = lane >> 4;
    int c8 = (lane & 15) << 3;
    const unsigned short* xbase = xh + hd * 128 + c8;
    float a0 = 0.f, a1 = 0.f, a2 = 0.f, a3 = 0.f, a4a = 0.f, a5 = 0.f, a6 = 0.f, a7 = 0.f;
    for (int k = wv; k < deg; k += 2) {
      int s = ssrc[k];
      float p = sp[k][hd];
      u16x8 xv = *(const u16x8*)(xbase + (size_t)s * 512);
      a0 += p * b2f(xv[0]); a1 += p * b2f(xv[1]);
      a2 += p * b2f(xv[2]); a3 += p * b2f(xv[3]);
      a4a += p * b2f(xv[4]); a5 += p * b2f(xv[5]);
      a6 += p * b2f(xv[6]); a7 += p * b2f(xv[7]);
    }
    float invh = 1.f / (sreds[hd] + sreds[4 + hd] + 1e-16f);
    float* so = &sout[wv * 512 + hd * 128 + c8];
    *(float4*)so       = make_float4(a0 * invh, a1 * invh, a2 * invh, a3 * invh);
    *(float4*)(so + 4) = make_float4(a4a * invh, a5 * invh, a6 * invh, a7 * invh);
    __syncthreads();
    float val = 0.f;
    #pragma unroll
    for (int hh = 0; hh < 4; ++hh)
      val += sout[hh * 128 + tid] + sout[512 + hh * 128 + tid];
    val = 0.25f * val + bias[tid];
    val = val > 0.f ? val : __expf(val) - 1.f;  // elu
    size_t o = (size_t)node * 128 + tid;
    h[o] = val + h[o];
    return;
  }

  // generic fallback (deg > 128)
  float lm0 = -1e30f, lm1 = -1e30f, lm2 = -1e30f, lm3 = -1e30f;
  for (int idx = begin + tid; idx < end; idx += 128) {
    int s = edge_src[idx];
    float4 a4 = *(const float4*)(als + (size_t)s * 4);
    lm0 = fmaxf(lm0, lrelu(a4.x + ad4.x));
    lm1 = fmaxf(lm1, lrelu(a4.y + ad4.y));
    lm2 = fmaxf(lm2, lrelu(a4.z + ad4.z));
    lm3 = fmaxf(lm3, lrelu(a4.w + ad4.w));
  }
  red[tid] = lm0; red[128 + tid] = lm1; red[256 + tid] = lm2; red[384 + tid] = lm3;
  __syncthreads();
  for (int off = 64; off > 0; off >>= 1) {
    if (tid < off) {
      red[tid]       = fmaxf(red[tid],       red[tid + off]);
      red[128 + tid] = fmaxf(red[128 + tid], red[128 + tid + off]);
      red[256 + tid] = fmaxf(red[256 + tid], red[256 + tid + off]);
      red[384 + tid] = fmaxf(red[384 + tid], red[384 + tid + off]);
    }
    __syncthreads();
  }
  float m0 = red[0], m1 = red[128], m2 = red[256], m3 = red[384];
  __syncthreads();
  float ls0 = 0.f, ls1 = 0.f, ls2 = 0.f, ls3 = 0.f;
  for (int idx = begin + tid; idx < end; idx += 128) {
    int s = edge_src[idx];
    float4 a4 = *(const float4*)(als + (size_t)s * 4);
    ls0 += __expf(lrelu(a4.x + ad4.x) - m0);
    ls1 += __expf(lrelu(a4.y + ad4.y) - m1);
    ls2 += __expf(lrelu(a4.z + ad4.z) - m2);
    ls3 += __expf(lrelu(a4.w + ad4.w) - m3);
  }
  red[tid] = ls0; red[128 + tid] = ls1; red[256 + tid] = ls2; red[384 + tid] = ls3;
  __syncthreads();
  for (int off = 64; off > 0; off >>= 1) {
    if (tid < off) {
      red[tid]       += red[tid + off];
      red[128 + tid] += red[128 + tid + off];
      red[256 + tid] += red[256 + tid + off];
      red[384 + tid] += red[384 + tid + off];
    }
    __syncthreads();
  }
  float inv0 = 1.f / (red[0]   + 1e-16f);
  float inv1 = 1.f / (red[128] + 1e-16f);
  float inv2 = 1.f / (red[256] + 1e-16f);
  float inv3 = 1.f / (red[384] + 1e-16f);
  float acc0 = 0.f, acc1 = 0.f, acc2 = 0.f, acc3 = 0.f;
  for (int idx = begin; idx < end; ++idx) {
    int s = edge_src[idx];
    float4 a4 = *(const float4*)(als + (size_t)s * 4);
    float al0 = __expf(lrelu(a4.x + ad4.x) - m0) * inv0;
    float al1 = __expf(lrelu(a4.y + ad4.y) - m1) * inv1;
    float al2 = __expf(lrelu(a4.z + ad4.z) - m2) * inv2;
    float al3 = __expf(lrelu(a4.w + ad4.w) - m3) * inv3;
    const unsigned short* xr = xh + (size_t)s * 512;
    acc0 += al0 * b2f(xr[tid]);
    acc1 += al1 * b2f(xr[128 + tid]);
    acc2 += al2 * b2f(xr[256 + tid]);
    acc3 += al3 * b2f(xr[384 + tid]);
  }
  float val = 0.25f * (acc0 + acc1 + acc2 + acc3) + bias[tid];
  val = val > 0.f ? val : __expf(val) - 1.f;
  size_t o = (size_t)node * 128 + tid;
  h[o] = val + h[o];
}

// ---------------- modal gating ----------------
__global__ __launch_bounds__(128) void k_modal(const float* __restrict__ hv,
                                               const float* __restrict__ ht,
                                               const float* __restrict__ mw,
                                               const float* __restrict__ mb,
                                               float* __restrict__ out) {
  int node = blockIdx.x, t = threadIdx.x;
  __shared__ float red[128];
  float a = hv[(size_t)node * 128 + t];
  float b = ht[(size_t)node * 128 + t];
  red[t] = a * mw[t] + b * mw[128 + t];
  __syncthreads();
  for (int off = 64; off > 0; off >>= 1) {
    if (t < off) red[t] += red[t + off];
    __syncthreads();
  }
  float beta = 1.f / (1.f + expf(-(red[0] + mb[0])));
  out[(size_t)node * 128 + t] = beta * a + (1.f - beta) * b;
}

extern "C" void kernel_launch(void* const* d_in, const int* in_sizes, int n_in,
                              void* d_out, int out_size, void* d_ws, size_t ws_size,
                              hipStream_t stream) {
  const float* x    = (const float*)d_in[0];
  const int*   ei   = (const int*)d_in[1];
  const float* vpw  = (const float*)d_in[2];
  const float* vpb  = (const float*)d_in[3];
  const float* tpw  = (const float*)d_in[4];
  const float* tpb  = (const float*)d_in[5];
  const float* vgw  = (const float*)d_in[6];
  const float* vgas = (const float*)d_in[7];
  const float* vgad = (const float*)d_in[8];
  const float* vgb  = (const float*)d_in[9];
  const float* tgw  = (const float*)d_in[10];
  const float* tgas = (const float*)d_in[11];
  const float* tgad = (const float*)d_in[12];
  const float* tgb  = (const float*)d_in[13];
  const float* mw   = (const float*)d_in[14];
  const float* mb   = (const float*)d_in[15];
  const float* vhw  = (const float*)d_in[16];
  const float* vhb  = (const float*)d_in[17];
  const float* thw  = (const float*)d_in[18];
  const float* thb  = (const float*)d_in[19];
  float* out = (float*)d_out;

  char* ws = (char*)d_ws;
  float*          h_v      = (float*)(ws);                         // 10,240,000
  float*          h_t      = (float*)(ws + 10240000);              // 10,240,000
  unsigned short* xhb_v    = (unsigned short*)(ws + 20480000);     // 20,480,000
  unsigned short* xhb_t    = (unsigned short*)(ws + 40960000);     // 20,480,000
  float*          als_v    = (float*)(ws + 61440000);              //    320,000
  float*          ald_v    = (float*)(ws + 61760000);              //    320,000
  float*          als_t    = (float*)(ws + 62080000);              //    320,000
  float*          ald_t    = (float*)(ws + 62400000);              //    320,000
  int*            row_ptr  = (int*)  (ws + 62720000);              //     80,016
  int*            deg      = (int*)  (ws + 62800016);              //     80,000
  int*            edge_src = (int*)  (ws + 62880016);              //  1,360,000
  unsigned short* bt       = (unsigned short*)(ws + 64240016);     //    884,736

  unsigned short* bt_vp = bt;            // [128][768]
  unsigned short* bt_tp = bt + 98304;    // [128][384]
  unsigned short* bt_vg = bt + 147456;   // 2 x [512][128]
  unsigned short* bt_tg = bt + 278528;   // 2 x [512][128]
  unsigned short* bt_vh = bt + 409600;   // [128][128]
  unsigned short* bt_th = bt + 425984;   // [128][128]

  // merged weight prep (8 jobs)
  WtJobs jb;
  jb.src[0] = vpw;           jb.dst[0] = bt_vp;          jb.K[0] = 768; jb.N[0] = 128;
  jb.src[1] = tpw;           jb.dst[1] = bt_tp;          jb.K[1] = 384; jb.N[1] = 128;
  jb.src[2] = vgw;           jb.dst[2] = bt_vg;          jb.K[2] = 128; jb.N[2] = 512;
  jb.src[3] = vgw + 65536;   jb.dst[3] = bt_vg + 65536;  jb.K[3] = 128; jb.N[3] = 512;
  jb.src[4] = tgw;           jb.dst[4] = bt_tg;          jb.K[4] = 128; jb.N[4] = 512;
  jb.src[5] = tgw + 65536;   jb.dst[5] = bt_tg + 65536;  jb.K[5] = 128; jb.N[5] = 512;
  jb.src[6] = vhw;           jb.dst[6] = bt_vh;          jb.K[6] = 128; jb.N[6] = 128;
  jb.src[7] = thw;           jb.dst[7] = bt_th;          jb.K[7] = 128; jb.N[7] = 128;
  int accb = 0;
  for (int s = 0; s < 8; ++s) { accb += (jb.K[s] * jb.N[s]) / 256; jb.blk_end[s] = accb; }
  k_wt_all<<<accb, 256, 0, stream>>>(jb);

  // CSR build
  k_init_deg<<<(N_NODES + 255) / 256, 256, 0, stream>>>(deg);
  k_hist<<<(N_EDGES + 255) / 256, 256, 0, stream>>>(ei, deg);
  k_scan<<<1, 1024, 0, stream>>>(deg, row_ptr);
  k_scatter<<<(E_TOT + 255) / 256, 256, 0, stream>>>(ei, row_ptr, deg, edge_src);

  // projections
  k_proj<<<dim3(MT32, 2), 256, 0, stream>>>(x, bt_vp, bt_tp, vpb, tpb, h_v, h_t);

  // GAT layers (v and t merged per stage)
  for (int L = 0; L < 2; ++L) {
    LayerArgs la;
    la.h[0] = h_v;  la.h[1] = h_t;
    la.bt[0] = bt_vg + (size_t)L * 65536;  la.bt[1] = bt_tg + (size_t)L * 65536;
    la.as_[0] = vgas + L * 512;  la.as_[1] = tgas + L * 512;
    la.ad_[0] = vgad + L * 512;  la.ad_[1] = tgad + L * 512;
    la.xb[0] = xhb_v;  la.xb[1] = xhb_t;
    la.als[0] = als_v; la.als[1] = als_t;
    la.ald[0] = ald_v; la.ald[1] = ald_t;
    k_layer<<<dim3(MT32, 8), 256, 0, stream>>>(la);

    AggArgs ag;
    ag.xh[0] = xhb_v;  ag.xh[1] = xhb_t;
    ag.als[0] = als_v; ag.als[1] = als_t;
    ag.ald[0] = ald_v; ag.ald[1] = ald_t;
    ag.bias[0] = vgb + L * HID;  ag.bias[1] = tgb + L * HID;
    ag.h[0] = h_v;  ag.h[1] = h_t;
    k_agg<<<2 * N_NODES, 128, 0, stream>>>(ag, row_ptr, edge_src);
  }

  // epilogue
  k_modal<<<N_NODES, 128, 0, stream>>>(h_v, h_t, mw, mb, out);
  k_head<<<dim3(MT32, 2), 256, 0, stream>>>(h_v, h_t, bt_vh, bt_th, vhb, thb, out);
}

// Round 8
// 424.955 us; speedup vs baseline: 1.1259x; 1.1259x over previous
//
#include <hip/hip_runtime.h>
#include <math.h>

#define N_NODES 20000
#define N_EDGES 320000
#define E_TOT   (N_EDGES + N_NODES)
#define HID     128
#define NEG_SLOPE 0.2f
#define MT64    313   // ceil(20000/64)

typedef __attribute__((ext_vector_type(8))) short short8;
typedef __attribute__((ext_vector_type(8))) unsigned short u16x8;
typedef __attribute__((ext_vector_type(4))) float f32x4;

__device__ __forceinline__ unsigned short f2b(float f) {
  unsigned u = __builtin_bit_cast(unsigned, f);
  return (unsigned short)((u + 0x7fffu + ((u >> 16) & 1u)) >> 16);
}
__device__ __forceinline__ float b2f(unsigned short h) {
  unsigned u = ((unsigned)h) << 16;
  return __builtin_bit_cast(float, u);
}
__device__ __forceinline__ unsigned pk2(float a, float b) {
  return (unsigned)f2b(a) | ((unsigned)f2b(b) << 16);
}
__device__ __forceinline__ float lrelu(float x) { return x > 0.f ? x : NEG_SLOPE * x; }

// ---------------- CSR build ----------------
__global__ void k_init_deg(int* __restrict__ deg) {
  int i = blockIdx.x * blockDim.x + threadIdx.x;
  if (i < N_NODES) deg[i] = 1;  // self loop
}

__global__ void k_hist(const int* __restrict__ ei, int* __restrict__ deg) {
  int e = blockIdx.x * blockDim.x + threadIdx.x;
  if (e < N_EDGES) atomicAdd(&deg[ei[N_EDGES + e]], 1);
}

__global__ __launch_bounds__(1024) void k_scan(int* __restrict__ deg,
                                               int* __restrict__ row_ptr) {
  __shared__ int sums[1024];
  int t = threadIdx.x;
  const int CH = 20;
  int begin = t * CH;
  int end = begin + CH; if (end > N_NODES) end = N_NODES;
  int loc = 0;
  for (int i = begin; i < end; ++i) loc += deg[i];
  sums[t] = loc;
  __syncthreads();
  for (int off = 1; off < 1024; off <<= 1) {
    int v = (t >= off) ? sums[t - off] : 0;
    __syncthreads();
    sums[t] += v;
    __syncthreads();
  }
  int run = (t > 0) ? sums[t - 1] : 0;
  for (int i = begin; i < end; ++i) {
    int d = deg[i];
    row_ptr[i] = run;
    run += d;
    deg[i] = 0;      // becomes the scatter cursor
  }
  if (t == 1023) row_ptr[N_NODES] = sums[1023];
}

__global__ void k_scatter(const int* __restrict__ ei, const int* __restrict__ row_ptr,
                          int* __restrict__ cursor, int* __restrict__ edge_src) {
  int t = blockIdx.x * blockDim.x + threadIdx.x;
  if (t < N_EDGES) {
    int s = ei[t], d = ei[N_EDGES + t];
    int pos = row_ptr[d] + atomicAdd(&cursor[d], 1);
    edge_src[pos] = s;
  } else if (t < E_TOT) {
    int i = t - N_EDGES;
    int pos = row_ptr[i] + atomicAdd(&cursor[i], 1);
    edge_src[pos] = i;
  }
}

// ---------------- merged weight prep ----------------
struct WtJobs {
  const float* src[8];
  unsigned short* dst[8];
  int K[8], N[8], blk_end[8];
};

__global__ void k_wt_all(WtJobs jb) {
  int b = blockIdx.x;
  int seg = 0;
  while (b >= jb.blk_end[seg]) ++seg;
  int base = seg ? jb.blk_end[seg - 1] : 0;
  int idx = (b - base) * 256 + threadIdx.x;
  int K = jb.K[seg], N = jb.N[seg];
  if (idx < N * K) {
    int n = idx / K, k = idx - n * K;
    jb.dst[seg][idx] = f2b(jb.src[seg][(size_t)k * N + n]);
  }
}

// ---------------- GEMM core: 64x128 tile, BK=128, 4 waves (2x2), deep loads ----------------
// Per K-step: 16 x 16B global loads in flight per thread, 32 MFMA, 2 barriers.
// K=128 ops (layer/head) run exactly ONE step. Swizzle: chunk ^ (row & 15), 2 lanes/bank.
// MODE 0: f32 out + bias + relu (LDS-coalesced).  MODE 1: bf16 out + fused attn logits.
template<int MODE>
__device__ __forceinline__ void gemm_core(
    const float* __restrict__ A, int lda, int c0,
    const unsigned short* __restrict__ Bt,
    const float* __restrict__ bias,
    float* __restrict__ Cf, unsigned short* __restrict__ Cb, int ldc,
    int M, int K, int m0, int n0,
    const float* __restrict__ asrc, const float* __restrict__ adst,
    float* __restrict__ als, float* __restrict__ ald, int head) {
  __shared__ unsigned short sAB[64 * 128 + 128 * 128];  // As(16KB) | Bs(32KB); reused as C-tile
  __shared__ float attS[64 * 2], attD[64 * 2];
  unsigned short* As = sAB;
  unsigned short* Bs = sAB + 64 * 128;

  int t = threadIdx.x;
  int w = t >> 6, l = t & 63;
  int wr = w >> 1, wc = w & 1;
  int lr = l & 15, lhi = l >> 4;

  int arow = t >> 2, aq = t & 3;      // A: 64 rows x 4 thr/row x 32 f32
  int brow = t >> 1, bhalf = t & 1;   // B: 128 rows x 2 thr/row x 64 bf16
  int agr = m0 + arow; if (agr > M - 1) agr = M - 1;  // clamp; OOB rows feed guarded stores only
  const float* aptr = A + (size_t)agr * lda + c0 + aq * 32;
  const unsigned short* bptr = Bt + (size_t)(n0 + brow) * K + bhalf * 64;

  f32x4 acc[2][4];
  #pragma unroll
  for (int i = 0; i < 2; ++i)
    #pragma unroll
    for (int j = 0; j < 4; ++j) acc[i][j] = (f32x4){0.f, 0.f, 0.f, 0.f};

  float4 ar[8];
  uint4  br[8];
  #pragma unroll
  for (int p = 0; p < 8; ++p) ar[p] = ((const float4*)aptr)[p];
  #pragma unroll
  for (int p = 0; p < 8; ++p) br[p] = ((const uint4*)bptr)[p];

  for (int k0 = 0; k0 < K; k0 += 128) {
    // regs -> LDS (A converts f32->bf16); chunk = 8 shorts (16B)
    #pragma unroll
    for (int p = 0; p < 4; ++p) {
      uint4 w4;
      w4.x = pk2(ar[2 * p].x, ar[2 * p].y);
      w4.y = pk2(ar[2 * p].z, ar[2 * p].w);
      w4.z = pk2(ar[2 * p + 1].x, ar[2 * p + 1].y);
      w4.w = pk2(ar[2 * p + 1].z, ar[2 * p + 1].w);
      int cb = aq * 4 + p;
      *(uint4*)&As[arow * 128 + ((cb ^ (arow & 15)) << 3)] = w4;
    }
    #pragma unroll
    for (int p = 0; p < 8; ++p) {
      int cb = bhalf * 8 + p;
      *(uint4*)&Bs[brow * 128 + ((cb ^ (brow & 15)) << 3)] = br[p];
    }
    __syncthreads();
    if (k0 + 128 < K) {   // prefetch next K-step while this one computes
      #pragma unroll
      for (int p = 0; p < 8; ++p) ar[p] = ((const float4*)(aptr + k0 + 128))[p];
      #pragma unroll
      for (int p = 0; p < 8; ++p) br[p] = ((const uint4*)(bptr + k0 + 128))[p];
    }
    #pragma unroll
    for (int kk = 0; kk < 4; ++kk) {
      short8 af[2], bfr[4];
      int cbf = lhi + kk * 4;
      #pragma unroll
      for (int i = 0; i < 2; ++i) {
        int row = wr * 32 + i * 16 + lr;
        af[i] = *(const short8*)&As[row * 128 + ((cbf ^ (row & 15)) << 3)];
      }
      #pragma unroll
      for (int j = 0; j < 4; ++j) {
        int nn = wc * 64 + j * 16 + lr;
        bfr[j] = *(const short8*)&Bs[nn * 128 + ((cbf ^ (nn & 15)) << 3)];
      }
      #pragma unroll
      for (int i = 0; i < 2; ++i)
        #pragma unroll
        for (int j = 0; j < 4; ++j)
          acc[i][j] = __builtin_amdgcn_mfma_f32_16x16x32_bf16(af[i], bfr[j], acc[i][j], 0, 0, 0);
    }
    __syncthreads();
  }

  if (MODE == 0) {
    float* Ctf = (float*)sAB;   // [64][128] f32 = 32 KB
    #pragma unroll
    for (int i = 0; i < 2; ++i)
      #pragma unroll
      for (int j = 0; j < 4; ++j) {
        int col = wc * 64 + j * 16 + lr;
        float bsv = bias[col];
        #pragma unroll
        for (int rr = 0; rr < 4; ++rr) {
          int row = wr * 32 + i * 16 + lhi * 4 + rr;
          float v = acc[i][j][rr] + bsv;
          Ctf[row * 128 + col] = fmaxf(v, 0.f);
        }
      }
    __syncthreads();
    int crow = t >> 2, cq = t & 3;
    int gr = m0 + crow;
    if (gr < M) {
      float4* gdst = (float4*)(Cf + (size_t)gr * ldc + cq * 32);
      const float4* ls = (const float4*)&Ctf[crow * 128 + cq * 32];
      #pragma unroll
      for (int p = 0; p < 8; ++p) gdst[p] = ls[p];
    }
  } else {
    // fused attention logits on bf16-rounded values (match stored xh)
    float asv[4], adv[4];
    #pragma unroll
    for (int j = 0; j < 4; ++j) {
      int col = wc * 64 + j * 16 + lr;
      asv[j] = asrc[col];
      adv[j] = adst[col];
    }
    #pragma unroll
    for (int i = 0; i < 2; ++i) {
      #pragma unroll
      for (int rr = 0; rr < 4; ++rr) {
        float ss = 0.f, sd = 0.f;
        #pragma unroll
        for (int j = 0; j < 4; ++j) {
          float v = b2f(f2b(acc[i][j][rr]));
          ss += v * asv[j];
          sd += v * adv[j];
        }
        ss += __shfl_xor(ss, 1); sd += __shfl_xor(sd, 1);
        ss += __shfl_xor(ss, 2); sd += __shfl_xor(sd, 2);
        ss += __shfl_xor(ss, 4); sd += __shfl_xor(sd, 4);
        ss += __shfl_xor(ss, 8); sd += __shfl_xor(sd, 8);
        if (lr == 0) {
          int row = wr * 32 + i * 16 + lhi * 4 + rr;
          attS[row * 2 + wc] = ss;
          attD[row * 2 + wc] = sd;
        }
      }
    }
    unsigned short* Ct = sAB;   // [64][128] bf16 = 16 KB
    #pragma unroll
    for (int i = 0; i < 2; ++i)
      #pragma unroll
      for (int j = 0; j < 4; ++j) {
        int col = wc * 64 + j * 16 + lr;
        #pragma unroll
        for (int rr = 0; rr < 4; ++rr) {
          int row = wr * 32 + i * 16 + lhi * 4 + rr;
          Ct[row * 128 + col] = f2b(acc[i][j][rr]);
        }
      }
    __syncthreads();
    if (t < 64) {
      int gr = m0 + t;
      if (gr < M) {
        als[gr * 4 + head] = attS[t * 2] + attS[t * 2 + 1];
        ald[gr * 4 + head] = attD[t * 2] + attD[t * 2 + 1];
      }
    }
    int crow = t >> 2, cq = t & 3;
    int gr = m0 + crow;
    if (gr < M) {
      uint4* gdst = (uint4*)(Cb + (size_t)gr * ldc + n0 + cq * 32);
      const uint4* ls = (const uint4*)&Ct[crow * 128 + cq * 32];
      #pragma unroll
      for (int p = 0; p < 4; ++p) gdst[p] = ls[p];
    }
  }
}

// projections: y=0 vis (K=768), y=1 txt (K=384)
__global__ __launch_bounds__(256) void k_proj(
    const float* __restrict__ x,
    const unsigned short* __restrict__ btv, const unsigned short* __restrict__ btt,
    const float* __restrict__ vb, const float* __restrict__ tb,
    float* __restrict__ hv, float* __restrict__ ht) {
  int m0 = blockIdx.x * 64;
  int c0, K;
  const unsigned short* Bt;
  const float* bias;
  float* Cf;
  if (blockIdx.y == 0) { c0 = 0;   K = 768; Bt = btv; bias = vb; Cf = hv; }
  else                 { c0 = 768; K = 384; Bt = btt; bias = tb; Cf = ht; }
  gemm_core<0>(x, 1152, c0, Bt, bias, Cf, nullptr, 128, N_NODES, K, m0, 0,
               nullptr, nullptr, nullptr, nullptr, 0);
}

// merged layer GEMM + fused attention; y = head + 4*mod (single K-step: K=128)
struct LayerArgs {
  const float* h[2];
  const unsigned short* bt[2];
  const float* as_[2];
  const float* ad_[2];
  unsigned short* xb[2];
  float* als[2];
  float* ald[2];
};
__global__ __launch_bounds__(256) void k_layer(LayerArgs a) {
  int m0 = blockIdx.x * 64;
  int head = blockIdx.y & 3, mod = blockIdx.y >> 2;
  gemm_core<1>(a.h[mod], 128, 0, a.bt[mod], nullptr, nullptr, a.xb[mod], 512,
               N_NODES, 128, m0, head * 128, a.as_[mod] + head * 128,
               a.ad_[mod] + head * 128, a.als[mod], a.ald[mod], head);
}

// merged head GEMMs: y=0 vision, y=1 text (single K-step)
__global__ __launch_bounds__(256) void k_head(
    const float* __restrict__ hv, const float* __restrict__ ht,
    const unsigned short* __restrict__ btvh, const unsigned short* __restrict__ btth,
    const float* __restrict__ vhb, const float* __restrict__ thb,
    float* __restrict__ out) {
  int m0 = blockIdx.x * 64;
  const float* A;
  const unsigned short* Bt;
  const float* bias;
  float* Cf;
  if (blockIdx.y == 0) { A = hv; Bt = btvh; bias = vhb; Cf = out + 2560000; }
  else                 { A = ht; Bt = btth; bias = thb; Cf = out + 5120000; }
  gemm_core<0>(A, 128, 0, Bt, bias, Cf, nullptr, 128, N_NODES, 128, m0, 0,
               nullptr, nullptr, nullptr, nullptr, 0);
}

// ---------------- fused GAT aggregation, both modalities in one grid ----------------
struct AggArgs {
  const unsigned short* xh[2];
  const float* als[2];
  const float* ald[2];
  const float* bias[2];
  float* h[2];
};
__global__ __launch_bounds__(128) void k_agg(AggArgs ag,
                                             const int* __restrict__ row_ptr,
                                             const int* __restrict__ edge_src) {
  int b = blockIdx.x;
  int mod = b >= N_NODES;
  int node = b - mod * N_NODES;
  const unsigned short* __restrict__ xh = ag.xh[mod];
  const float* __restrict__ als = ag.als[mod];
  const float* __restrict__ ald = ag.ald[mod];
  const float* __restrict__ bias = ag.bias[mod];
  float* __restrict__ h = ag.h[mod];

  int tid = threadIdx.x;  // 0..127
  __shared__ float sp[128][4];
  __shared__ int   ssrc[128];
  __shared__ float sredm[8], sreds[8];
  __shared__ float sout[1024];    // [2 waves][4 heads][128 ch]
  __shared__ float red[4 * 128];  // fallback only
  int begin = row_ptr[node], end = row_ptr[node + 1];
  int deg = end - begin;
  float4 ad4 = *(const float4*)(ald + (size_t)node * 4);
  int wv = tid >> 6;

  if (deg <= 128) {
    float e0 = -1e30f, e1 = -1e30f, e2 = -1e30f, e3 = -1e30f;
    if (tid < deg) {
      int s = edge_src[begin + tid];
      ssrc[tid] = s;
      float4 a4 = *(const float4*)(als + (size_t)s * 4);
      e0 = lrelu(a4.x + ad4.x); e1 = lrelu(a4.y + ad4.y);
      e2 = lrelu(a4.z + ad4.z); e3 = lrelu(a4.w + ad4.w);
    }
    float m0 = e0, m1 = e1, m2 = e2, m3 = e3;
    for (int off = 32; off > 0; off >>= 1) {
      m0 = fmaxf(m0, __shfl_xor(m0, off));
      m1 = fmaxf(m1, __shfl_xor(m1, off));
      m2 = fmaxf(m2, __shfl_xor(m2, off));
      m3 = fmaxf(m3, __shfl_xor(m3, off));
    }
    if ((tid & 63) == 0) {
      sredm[wv * 4 + 0] = m0; sredm[wv * 4 + 1] = m1;
      sredm[wv * 4 + 2] = m2; sredm[wv * 4 + 3] = m3;
    }
    __syncthreads();
    m0 = fmaxf(sredm[0], sredm[4]); m1 = fmaxf(sredm[1], sredm[5]);
    m2 = fmaxf(sredm[2], sredm[6]); m3 = fmaxf(sredm[3], sredm[7]);
    float p0 = 0.f, p1 = 0.f, p2 = 0.f, p3 = 0.f;
    if (tid < deg) {
      p0 = __expf(e0 - m0); p1 = __expf(e1 - m1);
      p2 = __expf(e2 - m2); p3 = __expf(e3 - m3);
    }
    *(float4*)&sp[tid][0] = make_float4(p0, p1, p2, p3);
    float s0 = p0, s1 = p1, s2 = p2, s3 = p3;
    for (int off = 32; off > 0; off >>= 1) {
      s0 += __shfl_xor(s0, off); s1 += __shfl_xor(s1, off);
      s2 += __shfl_xor(s2, off); s3 += __shfl_xor(s3, off);
    }
    if ((tid & 63) == 0) {
      sreds[wv * 4 + 0] = s0; sreds[wv * 4 + 1] = s1;
      sreds[wv * 4 + 2] = s2; sreds[wv * 4 + 3] = s3;
    }
    __syncthreads();

    // phase C: wave wv handles edges wv, wv+2, ... ; lane owns (head, 8 channels)
    int lane = tid & 63;
    int hd = lane >> 4;
    int c8 = (lane & 15) << 3;
    const unsigned short* xbase = xh + hd * 128 + c8;
    float a0 = 0.f, a1 = 0.f, a2 = 0.f, a3 = 0.f, a4a = 0.f, a5 = 0.f, a6 = 0.f, a7 = 0.f;
    for (int k = wv; k < deg; k += 2) {
      int s = ssrc[k];
      float p = sp[k][hd];
      u16x8 xv = *(const u16x8*)(xbase + (size_t)s * 512);
      a0 += p * b2f(xv[0]); a1 += p * b2f(xv[1]);
      a2 += p * b2f(xv[2]); a3 += p * b2f(xv[3]);
      a4a += p * b2f(xv[4]); a5 += p * b2f(xv[5]);
      a6 += p * b2f(xv[6]); a7 += p * b2f(xv[7]);
    }
    float invh = 1.f / (sreds[hd] + sreds[4 + hd] + 1e-16f);
    float* so = &sout[wv * 512 + hd * 128 + c8];
    *(float4*)so       = make_float4(a0 * invh, a1 * invh, a2 * invh, a3 * invh);
    *(float4*)(so + 4) = make_float4(a4a * invh, a5 * invh, a6 * invh, a7 * invh);
    __syncthreads();
    float val = 0.f;
    #pragma unroll
    for (int hh = 0; hh < 4; ++hh)
      val += sout[hh * 128 + tid] + sout[512 + hh * 128 + tid];
    val = 0.25f * val + bias[tid];
    val = val > 0.f ? val : __expf(val) - 1.f;  // elu
    size_t o = (size_t)node * 128 + tid;
    h[o] = val + h[o];
    return;
  }

  // generic fallback (deg > 128)
  float lm0 = -1e30f, lm1 = -1e30f, lm2 = -1e30f, lm3 = -1e30f;
  for (int idx = begin + tid; idx < end; idx += 128) {
    int s = edge_src[idx];
    float4 a4 = *(const float4*)(als + (size_t)s * 4);
    lm0 = fmaxf(lm0, lrelu(a4.x + ad4.x));
    lm1 = fmaxf(lm1, lrelu(a4.y + ad4.y));
    lm2 = fmaxf(lm2, lrelu(a4.z + ad4.z));
    lm3 = fmaxf(lm3, lrelu(a4.w + ad4.w));
  }
  red[tid] = lm0; red[128 + tid] = lm1; red[256 + tid] = lm2; red[384 + tid] = lm3;
  __syncthreads();
  for (int off = 64; off > 0; off >>= 1) {
    if (tid < off) {
      red[tid]       = fmaxf(red[tid],       red[tid + off]);
      red[128 + tid] = fmaxf(red[128 + tid], red[128 + tid + off]);
      red[256 + tid] = fmaxf(red[256 + tid], red[256 + tid + off]);
      red[384 + tid] = fmaxf(red[384 + tid], red[384 + tid + off]);
    }
    __syncthreads();
  }
  float m0 = red[0], m1 = red[128], m2 = red[256], m3 = red[384];
  __syncthreads();
  float ls0 = 0.f, ls1 = 0.f, ls2 = 0.f, ls3 = 0.f;
  for (int idx = begin + tid; idx < end; idx += 128) {
    int s = edge_src[idx];
    float4 a4 = *(const float4*)(als + (size_t)s * 4);
    ls0 += __expf(lrelu(a4.x + ad4.x) - m0);
    ls1 += __expf(lrelu(a4.y + ad4.y) - m1);
    ls2 += __expf(lrelu(a4.z + ad4.z) - m2);
    ls3 += __expf(lrelu(a4.w + ad4.w) - m3);
  }
  red[tid] = ls0; red[128 + tid] = ls1; red[256 + tid] = ls2; red[384 + tid] = ls3;
  __syncthreads();
  for (int off = 64; off > 0; off >>= 1) {
    if (tid < off) {
      red[tid]       += red[tid + off];
      red[128 + tid] += red[128 + tid + off];
      red[256 + tid] += red[256 + tid + off];
      red[384 + tid] += red[384 + tid + off];
    }
    __syncthreads();
  }
  float inv0 = 1.f / (red[0]   + 1e-16f);
  float inv1 = 1.f / (red[128] + 1e-16f);
  float inv2 = 1.f / (red[256] + 1e-16f);
  float inv3 = 1.f / (red[384] + 1e-16f);
  float acc0 = 0.f, acc1 = 0.f, acc2 = 0.f, acc3 = 0.f;
  for (int idx = begin; idx < end; ++idx) {
    int s = edge_src[idx];
    float4 a4 = *(const float4*)(als + (size_t)s * 4);
    float al0 = __expf(lrelu(a4.x + ad4.x) - m0) * inv0;
    float al1 = __expf(lrelu(a4.y + ad4.y) - m1) * inv1;
    float al2 = __expf(lrelu(a4.z + ad4.z) - m2) * inv2;
    float al3 = __expf(lrelu(a4.w + ad4.w) - m3) * inv3;
    const unsigned short* xr = xh + (size_t)s * 512;
    acc0 += al0 * b2f(xr[tid]);
    acc1 += al1 * b2f(xr[128 + tid]);
    acc2 += al2 * b2f(xr[256 + tid]);
    acc3 += al3 * b2f(xr[384 + tid]);
  }
  float val = 0.25f * (acc0 + acc1 + acc2 + acc3) + bias[tid];
  val = val > 0.f ? val : __expf(val) - 1.f;
  size_t o = (size_t)node * 128 + tid;
  h[o] = val + h[o];
}

// ---------------- modal gating ----------------
__global__ __launch_bounds__(128) void k_modal(const float* __restrict__ hv,
                                               const float* __restrict__ ht,
                                               const float* __restrict__ mw,
                                               const float* __restrict__ mb,
                                               float* __restrict__ out) {
  int node = blockIdx.x, t = threadIdx.x;
  __shared__ float red[128];
  float a = hv[(size_t)node * 128 + t];
  float b = ht[(size_t)node * 128 + t];
  red[t] = a * mw[t] + b * mw[128 + t];
  __syncthreads();
  for (int off = 64; off > 0; off >>= 1) {
    if (t < off) red[t] += red[t + off];
    __syncthreads();
  }
  float beta = 1.f / (1.f + expf(-(red[0] + mb[0])));
  out[(size_t)node * 128 + t] = beta * a + (1.f - beta) * b;
}

extern "C" void kernel_launch(void* const* d_in, const int* in_sizes, int n_in,
                              void* d_out, int out_size, void* d_ws, size_t ws_size,
                              hipStream_t stream) {
  const float* x    = (const float*)d_in[0];
  const int*   ei   = (const int*)d_in[1];
  const float* vpw  = (const float*)d_in[2];
  const float* vpb  = (const float*)d_in[3];
  const float* tpw  = (const float*)d_in[4];
  const float* tpb  = (const float*)d_in[5];
  const float* vgw  = (const float*)d_in[6];
  const float* vgas = (const float*)d_in[7];
  const float* vgad = (const float*)d_in[8];
  const float* vgb  = (const float*)d_in[9];
  const float* tgw  = (const float*)d_in[10];
  const float* tgas = (const float*)d_in[11];
  const float* tgad = (const float*)d_in[12];
  const float* tgb  = (const float*)d_in[13];
  const float* mw   = (const float*)d_in[14];
  const float* mb   = (const float*)d_in[15];
  const float* vhw  = (const float*)d_in[16];
  const float* vhb  = (const float*)d_in[17];
  const float* thw  = (const float*)d_in[18];
  const float* thb  = (const float*)d_in[19];
  float* out = (float*)d_out;

  char* ws = (char*)d_ws;
  float*          h_v      = (float*)(ws);                         // 10,240,000
  float*          h_t      = (float*)(ws + 10240000);              // 10,240,000
  unsigned short* xhb_v    = (unsigned short*)(ws + 20480000);     // 20,480,000
  unsigned short* xhb_t    = (unsigned short*)(ws + 40960000);     // 20,480,000
  float*          als_v    = (float*)(ws + 61440000);              //    320,000
  float*          ald_v    = (float*)(ws + 61760000);              //    320,000
  float*          als_t    = (float*)(ws + 62080000);              //    320,000
  float*          ald_t    = (float*)(ws + 62400000);              //    320,000
  int*            row_ptr  = (int*)  (ws + 62720000);              //     80,016
  int*            deg      = (int*)  (ws + 62800016);              //     80,000
  int*            edge_src = (int*)  (ws + 62880016);              //  1,360,000
  unsigned short* bt       = (unsigned short*)(ws + 64240016);     //    884,736

  unsigned short* bt_vp = bt;            // [128][768]
  unsigned short* bt_tp = bt + 98304;    // [128][384]
  unsigned short* bt_vg = bt + 147456;   // 2 x [512][128]
  unsigned short* bt_tg = bt + 278528;   // 2 x [512][128]
  unsigned short* bt_vh = bt + 409600;   // [128][128]
  unsigned short* bt_th = bt + 425984;   // [128][128]

  // merged weight prep (8 jobs)
  WtJobs jb;
  jb.src[0] = vpw;           jb.dst[0] = bt_vp;          jb.K[0] = 768; jb.N[0] = 128;
  jb.src[1] = tpw;           jb.dst[1] = bt_tp;          jb.K[1] = 384; jb.N[1] = 128;
  jb.src[2] = vgw;           jb.dst[2] = bt_vg;          jb.K[2] = 128; jb.N[2] = 512;
  jb.src[3] = vgw + 65536;   jb.dst[3] = bt_vg + 65536;  jb.K[3] = 128; jb.N[3] = 512;
  jb.src[4] = tgw;           jb.dst[4] = bt_tg;          jb.K[4] = 128; jb.N[4] = 512;
  jb.src[5] = tgw + 65536;   jb.dst[5] = bt_tg + 65536;  jb.K[5] = 128; jb.N[5] = 512;
  jb.src[6] = vhw;           jb.dst[6] = bt_vh;          jb.K[6] = 128; jb.N[6] = 128;
  jb.src[7] = thw;           jb.dst[7] = bt_th;          jb.K[7] = 128; jb.N[7] = 128;
  int accb = 0;
  for (int s = 0; s < 8; ++s) { accb += (jb.K[s] * jb.N[s]) / 256; jb.blk_end[s] = accb; }
  k_wt_all<<<accb, 256, 0, stream>>>(jb);

  // CSR build
  k_init_deg<<<(N_NODES + 255) / 256, 256, 0, stream>>>(deg);
  k_hist<<<(N_EDGES + 255) / 256, 256, 0, stream>>>(ei, deg);
  k_scan<<<1, 1024, 0, stream>>>(deg, row_ptr);
  k_scatter<<<(E_TOT + 255) / 256, 256, 0, stream>>>(ei, row_ptr, deg, edge_src);

  // projections
  k_proj<<<dim3(MT64, 2), 256, 0, stream>>>(x, bt_vp, bt_tp, vpb, tpb, h_v, h_t);

  // GAT layers (v and t merged per stage)
  for (int L = 0; L < 2; ++L) {
    LayerArgs la;
    la.h[0] = h_v;  la.h[1] = h_t;
    la.bt[0] = bt_vg + (size_t)L * 65536;  la.bt[1] = bt_tg + (size_t)L * 65536;
    la.as_[0] = vgas + L * 512;  la.as_[1] = tgas + L * 512;
    la.ad_[0] = vgad + L * 512;  la.ad_[1] = tgad + L * 512;
    la.xb[0] = xhb_v;  la.xb[1] = xhb_t;
    la.als[0] = als_v; la.als[1] = als_t;
    la.ald[0] = ald_v; la.ald[1] = ald_t;
    k_layer<<<dim3(MT64, 8), 256, 0, stream>>>(la);

    AggArgs ag;
    ag.xh[0] = xhb_v;  ag.xh[1] = xhb_t;
    ag.als[0] = als_v; ag.als[1] = als_t;
    ag.ald[0] = ald_v; ag.ald[1] = ald_t;
    ag.bias[0] = vgb + L * HID;  ag.bias[1] = tgb + L * HID;
    ag.h[0] = h_v;  ag.h[1] = h_t;
    k_agg<<<2 * N_NODES, 128, 0, stream>>>(ag, row_ptr, edge_src);
  }

  // epilogue
  k_modal<<<N_NODES, 128, 0, stream>>>(h_v, h_t, mw, mb, out);
  k_head<<<dim3(MT64, 2), 256, 0, stream>>>(h_v, h_t, bt_vh, bt_th, vhb, thb, out);
}